// Round 2
// baseline (1988.663 us; speedup 1.0000x reference)
//
#include <hip/hip_runtime.h>

#define TT 2048
#define FF 12
#define CH 128
#define L2E 1.44269504088896340736f

typedef float v2f __attribute__((ext_vector_type(2)));

__device__ __forceinline__ float fast_exp2(float x){ return __builtin_amdgcn_exp2f(x); }
__device__ __forceinline__ float fast_rcp(float x){ return __builtin_amdgcn_rcpf(x); }
__device__ __forceinline__ v2f fma2(v2f a, v2f b, v2f c){ return __builtin_elementwise_fma(a, b, c); }
__device__ __forceinline__ v2f mk2(float x, float y){ v2f r; r.x = x; r.y = y; return r; }

// One block per batch element (256 blocks = 256 CUs), 256 threads = 4 waves
// (1 wave/SIMD, perfectly balanced). State vector v = [h(96) | x(24) | pad] in
// LDS, double-buffered. Each lane owns:
//   A: full 120-dot for gate row gA = qg*96 + q   (quad q=tid>>2 -> units 0..63)
//   B: half 60-dot for gate row gB = qg2*96 + 64+oc (octet oc=tid>>3 -> units 64..95),
//      half hf = tid&1, combined with one shfl_xor(1).
// Per step ONE barrier. Gate exchange via shfl_xor within quad/octet. The
// next step's x columns are copied into the v-buffer by 24 lanes pre-barrier
// (off the critical chain). No separate x-part segment, no cross-wave reduce.
__global__ __launch_bounds__(256, 1) void lstm_persist(
  const float* __restrict__ seq, const int* __restrict__ ev, const int* __restrict__ rsi,
  const int* __restrict__ len, const float* __restrict__ eemb, const float* __restrict__ remb,
  const float* __restrict__ W_ih, const float* __restrict__ W_hh,
  const float* __restrict__ b_ih, const float* __restrict__ b_hh,
  const float* __restrict__ W_mlp, const float* __restrict__ b_mlp,
  const float* __restrict__ W_fc, const float* __restrict__ b_fc,
  float* __restrict__ out)
{
  const int b   = blockIdx.x;
  const int tid = threadIdx.x;
  const int qg  = tid & 3;      // A gate: 0=i 1=f 2=g 3=o
  const int q   = tid >> 2;     // A unit 0..63
  const int oc  = tid >> 3;     // octet -> B unit 64+oc
  const int s   = tid & 7;
  const int qg2 = s >> 1;       // B gate
  const int hf  = s & 1;        // B half: cols [hf*60, hf*60+60)
  const int gA  = qg*96  + q;
  const int gB  = qg2*96 + 64 + oc;

  __shared__ __align__(16) float vv[2][128];    // [parity][0..95 h | 96..119 x | pad]
  __shared__ __align__(16) float xf[CH*24];     // staged chunk rows, 24 floats each
  __shared__ __align__(16) float lastk[3*96];
  __shared__ __align__(16) float et[192];
  __shared__ __align__(16) float rt[24];
  __shared__ __align__(16) float accs[192];
  __shared__ __align__(16) float h2[2*96];
  __shared__ int evb[CH];
  __shared__ int rsb[CH];

  // ---- prologue: per-lane weight rows into registers ----
  v2f wA[60];
  #pragma unroll
  for (int k = 0; k < 60; ++k) {
    const int c0 = 2*k, c1 = 2*k + 1;
    const float w0 = (c0 < 96) ? W_hh[gA*96 + c0] : ((c0 < 117) ? W_ih[gA*21 + (c0-96)] : 0.f);
    const float w1 = (c1 < 96) ? W_hh[gA*96 + c1] : ((c1 < 117) ? W_ih[gA*21 + (c1-96)] : 0.f);
    wA[k] = mk2(w0, w1);
  }
  v2f wB[30];
  #pragma unroll
  for (int k = 0; k < 30; ++k) {
    const int c0 = 2*k, c1 = 2*k + 1;
    const int d0 = hf*60 + c0, d1 = hf*60 + c1;
    const float w0 = (d0 < 96) ? W_hh[gB*96 + d0] : ((d0 < 117) ? W_ih[gB*21 + (d0-96)] : 0.f);
    const float w1 = (d1 < 96) ? W_hh[gB*96 + d1] : ((d1 < 117) ? W_ih[gB*21 + (d1-96)] : 0.f);
    wB[k] = mk2(w0, w1);
  }
  const float bgA = b_ih[gA] + b_hh[gA];
  const float bgB = (hf == 0) ? (b_ih[gB] + b_hh[gB]) : 0.f;

  ((float*)vv)[tid] = 0.f;                        // 256 floats: both buffers
  if (tid < 192) et[tid] = eemb[tid];
  if (tid < 24)  rt[tid] = remb[tid];
  for (int i = tid; i < 288; i += 256) lastk[i] = 0.f;

  float cA = 0.f, cB = 0.f;
  const int L = len[b];   // loop runs exactly L steps; outputs past L unused

  for (int t0 = 0; t0 < L; t0 += CH) {
    // ---- stage: coalesced seq chunk + indices ----
    #pragma unroll
    for (int qq = 0; qq < 6; ++qq) {
      const int i = tid + qq*256;                 // 0..1535 = CH*12
      const int r = i/12, c = i - r*12;
      xf[r*24 + c] = seq[(size_t)b*(TT*FF) + (size_t)t0*FF + i];
    }
    if (tid < CH) {
      evb[tid] = ev [b*TT + t0 + tid];
      rsb[tid] = rsi[b*TT + t0 + tid];
    }
    __syncthreads();
    // ---- embedding gather into cols 12..23 (21..23 zero) ----
    #pragma unroll
    for (int qq = 0; qq < 6; ++qq) {
      const int i = tid + qq*256;
      const int r = i/12, cc = i - r*12 + 12;
      float v;
      if (cc < 18)      v = et[evb[r]*6 + (cc-12)];
      else if (cc < 21) v = rt[rsb[r]*3 + (cc-18)];
      else              v = 0.f;
      xf[r*24 + cc] = v;
    }
    __syncthreads();
    // x columns for step 0 of this chunk (h is already in vv[0])
    if (tid < 24) vv[0][96 + tid] = xf[tid];
    __syncthreads();

    const int nr = min(CH, L - t0);
    for (int r = 0; r < nr; ++r) {
      const int p = r & 1;
      const float4* va = (const float4*)(vv[p]);            // broadcast
      const float4* vb = (const float4*)(vv[p] + hf*60);    // 2-way broadcast (free)

      // ---- A: full 120-dot (60 pk-FMA, 4 chains) ----
      v2f a0 = mk2(bgA, 0.f), a1 = mk2(0.f,0.f), a2 = mk2(0.f,0.f), a3 = mk2(0.f,0.f);
      // ---- B: half 60-dot (30 pk-FMA, 2 chains) ----
      v2f bb0 = mk2(bgB, 0.f), bb1 = mk2(0.f,0.f);
      #pragma unroll
      for (int k = 0; k < 15; ++k) {
        const float4 x0 = va[2*k];
        const float4 x1 = va[2*k+1];
        const float4 y0 = vb[k];
        a0  = fma2(wA[4*k+0], mk2(x0.x,x0.y), a0);
        a1  = fma2(wA[4*k+1], mk2(x0.z,x0.w), a1);
        a2  = fma2(wA[4*k+2], mk2(x1.x,x1.y), a2);
        a3  = fma2(wA[4*k+3], mk2(x1.z,x1.w), a3);
        bb0 = fma2(wB[2*k+0], mk2(y0.x,y0.y), bb0);
        bb1 = fma2(wB[2*k+1], mk2(y0.z,y0.w), bb1);
      }
      const v2f sa = (a0 + a1) + (a2 + a3);
      const float sA = sa.x + sa.y;
      const v2f sb = bb0 + bb1;
      float sB = sb.x + sb.y;
      sB += __shfl_xor(sB, 1);                    // combine halves (both lanes get full sum)

      // ---- activations (in-lane) ----
      const bool tA = (qg == 2);
      const float eA = fast_exp2(tA ? (-2.f*L2E)*fabsf(sA) : (-L2E)*sA);
      const float rA = fast_rcp(1.f + eA);
      const float aA = tA ? copysignf((1.f - eA)*rA, sA) : rA;
      const bool tB = (qg2 == 2);
      const float eB = fast_exp2(tB ? (-2.f*L2E)*fabsf(sB) : (-L2E)*sB);
      const float rB = fast_rcp(1.f + eB);
      const float aB = tB ? copysignf((1.f - eB)*rB, sB) : rB;

      // ---- gate exchange: depth-2 shuffles, all lanes active ----
      const float fA_ = __shfl_xor(aA, 1);
      const float gA_ = __shfl_xor(aA, 2);
      const float oA_ = __shfl_xor(fA_, 2);
      const float fB_ = __shfl_xor(aB, 2);
      const float gB_ = __shfl_xor(aB, 4);
      const float oB_ = __shfl_xor(fB_, 4);

      const int kk = (t0 + r) + 3 - L;            // last-K ring index
      // ---- unit update A (lane qg==0 owns unit q) ----
      if (qg == 0) {
        cA = fmaf(fA_, cA, aA * gA_);
        const float e2 = fast_exp2((-2.f*L2E)*fabsf(cA));
        const float th = copysignf((1.f - e2)*fast_rcp(1.f + e2), cA);
        const float hn = oA_ * th;
        vv[p^1][q] = hn;
        if (kk >= 0) lastk[kk*96 + q] = hn;
      }
      // ---- unit update B (lane s==0 owns unit 64+oc) ----
      if (s == 0) {
        cB = fmaf(fB_, cB, aB * gB_);
        const float e2 = fast_exp2((-2.f*L2E)*fabsf(cB));
        const float th = copysignf((1.f - e2)*fast_rcp(1.f + e2), cB);
        const float hn = oB_ * th;
        vv[p^1][64 + oc] = hn;
        if (kk >= 0) lastk[kk*96 + 64 + oc] = hn;
      }
      // ---- next-step x columns (off-chain copy, 24 lanes) ----
      if (qg == 1 && q < 24 && r + 1 < nr) vv[p^1][96 + q] = xf[(r+1)*24 + q];
      __syncthreads();
    }
  }

  // ---- epilogue ----
  const float* hfin = vv[L & 1];
  if (tid < 192) {
    const int half = tid / 96;
    const int m    = tid - half*96;
    const float* wp = W_mlp + m*288 + half*144;
    const float* xq = lastk + half*144;
    float ssum = 0.f;
    #pragma unroll 8
    for (int i = 0; i < 144; ++i) ssum = fmaf(wp[i], xq[i], ssum);
    accs[tid] = ssum;
  }
  __syncthreads();
  if (tid < 96) {
    const float hl = accs[tid] + accs[96+tid] + b_mlp[tid];
    h2[96 + tid] = fmaxf(hl, 0.f);
    h2[tid] = hfin[tid];
  }
  __syncthreads();
  if (tid < 128) {
    const int o  = tid >> 6;
    const int ll = tid & 63;
    const float* wf = W_fc + o*192 + 3*ll;
    float ssum = fmaf(wf[0], h2[3*ll+0], fmaf(wf[1], h2[3*ll+1], wf[2]*h2[3*ll+2]));
    #pragma unroll
    for (int off = 32; off > 0; off >>= 1) ssum += __shfl_down(ssum, off);
    if (ll == 0) out[b*2 + o] = ssum + b_fc[o];
  }
}

extern "C" void kernel_launch(void* const* d_in, const int* in_sizes, int n_in,
                              void* d_out, int out_size, void* d_ws, size_t ws_size,
                              hipStream_t stream) {
  const float* seq   = (const float*)d_in[0];
  const int*   ev    = (const int*)  d_in[1];
  const int*   rsi   = (const int*)  d_in[2];
  const int*   len   = (const int*)  d_in[3];
  const float* eemb  = (const float*)d_in[4];
  const float* remb  = (const float*)d_in[5];
  const float* W_ih  = (const float*)d_in[6];
  const float* W_hh  = (const float*)d_in[7];
  const float* b_ih  = (const float*)d_in[8];
  const float* b_hh  = (const float*)d_in[9];
  const float* W_mlp = (const float*)d_in[10];
  const float* b_mlp = (const float*)d_in[11];
  const float* W_fc  = (const float*)d_in[12];
  const float* b_fc  = (const float*)d_in[13];

  hipLaunchKernelGGL(lstm_persist, dim3(256), dim3(256), 0, stream,
                     seq, ev, rsi, len, eemb, remb, W_ih, W_hh, b_ih, b_hh,
                     W_mlp, b_mlp, W_fc, b_fc, (float*)d_out);
}

// Round 3
// 1478.762 us; speedup vs baseline: 1.3448x; 1.3448x over previous
//
#include <hip/hip_runtime.h>

#define TT 2048
#define FF 12
#define HH 96
#define CH 128
#define PST 66            // part row stride (floats): 2-way bank aliasing on write AND read
#define L2E 1.44269504088896340736f

typedef float v2f __attribute__((ext_vector_type(2)));

__device__ __forceinline__ float fast_exp2(float x){ return __builtin_amdgcn_exp2f(x); }
__device__ __forceinline__ float fast_rcp(float x){ return __builtin_amdgcn_rcpf(x); }
__device__ __forceinline__ v2f fma2(v2f a, v2f b, v2f c){ return __builtin_elementwise_fma(a, b, c); }
__device__ __forceinline__ v2f mk2(float x, float y){ v2f r; r.x = x; r.y = y; return r; }

// One block per batch element (256 blocks = 256 CUs), 512 threads = 8 waves.
// Baseline 8-wave skeleton (phase-parallel, proven fastest) with two changes:
//  (1) phase A uses v_pk_fma_f32 (48 pk-FMA/lane instead of 96 scalar) -> issue
//      per SIMD 384 -> 192 cycles.
//  (2) phases B and C merged: reduce-lane owns gate (u,qg) at tid=u*4+qg, so the
//      4 gates of a unit are an intra-quad; after in-lane activation, three
//      PARALLEL shfl_xor(1/2/3) (depth-1 swizzles) deliver f,g,o to the qg==0
//      lane which updates c,h. Removes one barrier + one LDS round trip.
__global__ __launch_bounds__(512, 2) void lstm_persist(
  const float* __restrict__ seq, const int* __restrict__ ev, const int* __restrict__ rsi,
  const int* __restrict__ len, const float* __restrict__ eemb, const float* __restrict__ remb,
  const float* __restrict__ W_ih, const float* __restrict__ W_hh,
  const float* __restrict__ b_ih, const float* __restrict__ b_hh,
  const float* __restrict__ W_mlp, const float* __restrict__ b_mlp,
  const float* __restrict__ W_fc, const float* __restrict__ b_fc,
  float* __restrict__ out)
{
  const int b   = blockIdx.x;
  const int tid = threadIdx.x;
  const int w   = tid >> 6;
  const int l   = tid & 63;

  __shared__ __align__(16) float vh[HH];          // h state
  __shared__ __align__(16) float xch[CH][32];     // staged x chunk, rows padded to 32 floats
  __shared__ __align__(16) float part[6*8*PST];   // [k][wave] rows of 66, [lane] offset
  __shared__ __align__(16) float lastk[3*HH];     // last-K h ring (zero-init)
  __shared__ __align__(16) float h2[2*HH];
  __shared__ __align__(16) float accs[192];
  __shared__ __align__(16) float et[32*6];
  __shared__ __align__(16) float rt[8*3];
  __shared__ int evb[CH];
  __shared__ int rsb[CH];

  // ---- prologue: per-lane weight slice (6 gates x 16 cols) as 48 v2f ----
  v2f wreg[48];
  if (w < 6) {
    #pragma unroll
    for (int k = 0; k < 6; ++k) {
      const int g = l + 64*k;
      const float* p = W_hh + g*96 + 16*w;
      #pragma unroll
      for (int i = 0; i < 8; ++i) wreg[k*8+i] = mk2(p[2*i], p[2*i+1]);
    }
  } else if (w == 6) {
    #pragma unroll
    for (int k = 0; k < 6; ++k) {
      const int g = l + 64*k;
      const float* p = W_ih + g*21;               // v-cols 96..111 -> W_ih[0..16)
      #pragma unroll
      for (int i = 0; i < 8; ++i) wreg[k*8+i] = mk2(p[2*i], p[2*i+1]);
    }
  } else {
    #pragma unroll
    for (int k = 0; k < 6; ++k) {
      const int g = l + 64*k;
      #pragma unroll
      for (int i = 0; i < 8; ++i) {               // v-cols 112..127 -> W_ih[16..21) then 0
        const int c0 = 16 + 2*i, c1 = 17 + 2*i;
        const float w0 = (c0 < 21) ? W_ih[g*21 + c0] : 0.f;
        const float w1 = (c1 < 21) ? W_ih[g*21 + c1] : 0.f;
        wreg[k*8+i] = mk2(w0, w1);
      }
    }
  }

  // ---- phase-B mapping: lane tid = u*4 + qg owns gate row gb = qg*96+u ----
  const int ub = tid >> 2;
  const int qb = tid & 3;                          // 0=i 1=f 2=g 3=o
  const int gb = qb*96 + ub;                       // valid only for tid<384
  const float bg = (tid < 384) ? (b_ih[gb] + b_hh[gb]) : 0.f;
  const int pk_ = gb >> 6;                         // part row-group
  const int pl_ = gb & 63;                         // part lane offset

  for (int i = tid; i < HH;   i += 512) vh[i] = 0.f;
  for (int i = tid; i < 3*HH; i += 512) lastk[i] = 0.f;
  for (int i = tid; i < 192;  i += 512) et[i] = eemb[i];
  for (int i = tid; i < 24;   i += 512) rt[i] = remb[i];

  float c_state = 0.f;
  const int L = len[b];                            // state frozen past L; outputs past L unused

  for (int t0 = 0; t0 < L; t0 += CH) {
    // ---- stage 1: coalesced seq load + index load ----
    for (int q = tid; q < CH*FF; q += 512) {
      const int r = q / 12;
      const int c = q - r*12;
      xch[r][c] = seq[(size_t)b*(TT*FF) + (size_t)t0*FF + q];
    }
    if (tid < CH) {
      evb[tid] = ev [b*TT + t0 + tid];
      rsb[tid] = rsi[b*TT + t0 + tid];
    }
    __syncthreads();
    // ---- stage 2: embedding gather + zero pad (cols 12..31) ----
    for (int q = tid; q < CH*20; q += 512) {
      const int r  = q / 20;
      const int cc = q - r*20 + 12;
      float val;
      if (cc < 18)      val = et[evb[r]*6 + (cc-12)];
      else if (cc < 21) val = rt[rsb[r]*3 + (cc-18)];
      else              val = 0.f;
      xch[r][cc] = val;
    }
    __syncthreads();

    const int nr = min(CH, L - t0);
    for (int r = 0; r < nr; ++r) {
      // ---- phase A: gate partials, all 8 waves, pk-FMA ----
      const float* sp = (w < 6) ? (vh + 16*w) : (&xch[r][16*(w-6)]);
      const float4 q0 = ((const float4*)sp)[0];
      const float4 q1 = ((const float4*)sp)[1];
      const float4 q2 = ((const float4*)sp)[2];
      const float4 q3 = ((const float4*)sp)[3];
      v2f xv[8];
      xv[0] = mk2(q0.x,q0.y); xv[1] = mk2(q0.z,q0.w);
      xv[2] = mk2(q1.x,q1.y); xv[3] = mk2(q1.z,q1.w);
      xv[4] = mk2(q2.x,q2.y); xv[5] = mk2(q2.z,q2.w);
      xv[6] = mk2(q3.x,q3.y); xv[7] = mk2(q3.z,q3.w);
      #pragma unroll
      for (int k = 0; k < 6; ++k) {
        v2f a0 = mk2(0.f,0.f), a1 = mk2(0.f,0.f), a2 = mk2(0.f,0.f), a3 = mk2(0.f,0.f);
        a0 = fma2(wreg[k*8+0], xv[0], a0);
        a1 = fma2(wreg[k*8+1], xv[1], a1);
        a2 = fma2(wreg[k*8+2], xv[2], a2);
        a3 = fma2(wreg[k*8+3], xv[3], a3);
        a0 = fma2(wreg[k*8+4], xv[4], a0);
        a1 = fma2(wreg[k*8+5], xv[5], a1);
        a2 = fma2(wreg[k*8+6], xv[6], a2);
        a3 = fma2(wreg[k*8+7], xv[7], a3);
        const v2f as = (a0 + a1) + (a2 + a3);
        part[(k*8 + w)*PST + l] = as.x + as.y;    // 2-way bank alias: free
      }
      __syncthreads();
      // ---- phase B+C merged: reduce + activate + quad-exchange + update ----
      if (tid < 384) {
        float s = bg;
        #pragma unroll
        for (int ww = 0; ww < 8; ++ww) s += part[(pk_*8 + ww)*PST + pl_];
        const bool is_t = (qb == 2);               // g-gate -> tanh, else sigmoid
        const float arg = is_t ? (-2.f*L2E)*fabsf(s) : (-L2E)*s;
        const float e  = fast_exp2(arg);
        const float r1 = fast_rcp(1.f + e);
        const float a  = is_t ? copysignf((1.f - e)*r1, s) : r1;
        // parallel depth-1 exchange within the quad
        const float t1 = __shfl_xor(a, 1);         // for qb==0: f
        const float t2 = __shfl_xor(a, 2);         // for qb==0: g
        const float t3 = __shfl_xor(a, 3);         // for qb==0: o
        if (qb == 0) {
          c_state = fmaf(t1, c_state, a * t2);     // f*c + i*g
          const float e2 = fast_exp2((-2.f*L2E)*fabsf(c_state));
          const float th = copysignf((1.f - e2)*fast_rcp(1.f + e2), c_state);
          const float hn = t3 * th;                // o * tanh(c)
          vh[ub] = hn;
          const int kk = (t0 + r) + 3 - L;         // last-K ring: t in [L-3, L)
          if (kk >= 0) lastk[kk*96 + ub] = hn;
        }
      }
      __syncthreads();
    }
  }

  // ---- epilogue: h_fin = vh; h_lastk = relu(W_mlp @ lastk + b); out = W_fc @ [h_fin|h_lastk] + b ----
  if (tid < 192) {
    const int hh = tid / 96;
    const int m  = tid - hh*96;
    const float* wp = W_mlp + m*288 + hh*144;
    const float* xp = lastk + hh*144;
    float s = 0.f;
    #pragma unroll 8
    for (int i = 0; i < 144; ++i) s = fmaf(wp[i], xp[i], s);
    accs[tid] = s;
  }
  __syncthreads();
  if (tid < 96) {
    const float hl = accs[tid] + accs[96+tid] + b_mlp[tid];
    h2[96 + tid] = fmaxf(hl, 0.f);
    h2[tid] = vh[tid];
  }
  __syncthreads();
  if (tid < 128) {
    const int o  = tid >> 6;
    const int ll = tid & 63;
    const float* wf = W_fc + o*192 + 3*ll;
    float s = fmaf(wf[0], h2[3*ll+0], fmaf(wf[1], h2[3*ll+1], wf[2]*h2[3*ll+2]));
    #pragma unroll
    for (int off = 32; off > 0; off >>= 1) s += __shfl_down(s, off);
    if (ll == 0) out[b*2 + o] = s + b_fc[o];
  }
}

extern "C" void kernel_launch(void* const* d_in, const int* in_sizes, int n_in,
                              void* d_out, int out_size, void* d_ws, size_t ws_size,
                              hipStream_t stream) {
  const float* seq   = (const float*)d_in[0];
  const int*   ev    = (const int*)  d_in[1];
  const int*   rsi   = (const int*)  d_in[2];
  const int*   len   = (const int*)  d_in[3];
  const float* eemb  = (const float*)d_in[4];
  const float* remb  = (const float*)d_in[5];
  const float* W_ih  = (const float*)d_in[6];
  const float* W_hh  = (const float*)d_in[7];
  const float* b_ih  = (const float*)d_in[8];
  const float* b_hh  = (const float*)d_in[9];
  const float* W_mlp = (const float*)d_in[10];
  const float* b_mlp = (const float*)d_in[11];
  const float* W_fc  = (const float*)d_in[12];
  const float* b_fc  = (const float*)d_in[13];

  hipLaunchKernelGGL(lstm_persist, dim3(256), dim3(512), 0, stream,
                     seq, ev, rsi, len, eemb, remb, W_ih, W_hh, b_ih, b_hh,
                     W_mlp, b_mlp, W_fc, b_fc, (float*)d_out);
}

// Round 5
// 1367.189 us; speedup vs baseline: 1.4546x; 1.0816x over previous
//
#include <hip/hip_runtime.h>

#define TT 2048
#define FF 12
#define HH 96
#define CH 128
#define L2E 1.44269504088896340736f

__device__ __forceinline__ float fast_exp2(float x){ return __builtin_amdgcn_exp2f(x); }
__device__ __forceinline__ float fast_rcp(float x){ return __builtin_amdgcn_rcpf(x); }

// DPP cross-lane at VALU rate. bound_ctrl=true -> OOB lanes read 0 (unused).
#define DPPF(x, ctrl) __int_as_float(__builtin_amdgcn_update_dpp(0, __float_as_int(x), (ctrl), 0xF, 0xF, true))
#define QP_XOR1 0xB1   // quad_perm [1,0,3,2]
#define QP_XOR2 0x4E   // quad_perm [2,3,0,1]
#define SHL4    0x104  // row_shl:4  -> dst[i] = src[i+4] (pull from higher lane)
#define SHL8    0x108
#define SHL12   0x10C

// One block per batch element (256 blocks = 256 CUs), 512 threads = 8 waves.
// 16-lane DPP group G (=tid>>4, 32 groups) owns units 3G..3G+2 = interleaved
// gate-rows 12G..12G+11 (row r' = 4*unit + gate). Quad q owns rows 3q..3q+2;
// lane c4 of the quad takes h-cols [24c4,24c4+24) and x-cols [6c4,6c4+6):
// 90 FMA/lane, identical on every wave (perfect SIMD balance).
// Dot reduce = quad_perm butterfly (VALU rate). Gate exchange = 9 row_shl DPP
// movs; lanes lu=0,1,2 of each group own c,h of units 3G+lu in registers.
// h is double-buffered in LDS, read as quad-broadcast float4 (conflict-free).
// ONE barrier per step; zero cross-wave LDS round-trips besides h itself.
__global__ __launch_bounds__(512, 2) void lstm_persist(
  const float* __restrict__ seq, const int* __restrict__ ev, const int* __restrict__ rsi,
  const int* __restrict__ len, const float* __restrict__ eemb, const float* __restrict__ remb,
  const float* __restrict__ W_ih, const float* __restrict__ W_hh,
  const float* __restrict__ b_ih, const float* __restrict__ b_hh,
  const float* __restrict__ W_mlp, const float* __restrict__ b_mlp,
  const float* __restrict__ W_fc, const float* __restrict__ b_fc,
  float* __restrict__ out)
{
  const int b   = blockIdx.x;
  const int tid = threadIdx.x;
  const int G   = tid >> 4;     // DPP 16-lane group, 0..31
  const int lu  = tid & 15;     // lane in group
  const int q   = lu >> 2;      // quad in group
  const int c4  = lu & 3;       // col-slice in quad

  __shared__ __align__(16) float vv[2][128];    // double-buffered h (96 used)
  __shared__ __align__(16) float xch[CH][32];   // staged x chunk, rows padded to 32
  __shared__ __align__(16) float lastk[3*HH];   // last-K h ring
  __shared__ __align__(16) float et[32*6];
  __shared__ __align__(16) float rt[8*3];
  __shared__ __align__(16) float accs[192];
  __shared__ __align__(16) float h2[2*HH];
  __shared__ int evb[CH];
  __shared__ int rsb[CH];

  // ---- prologue: per-lane weight slices (3 rows x (24 h + 6 x)) ----
  float wh[3][24];
  float wx[3][6];
  float bg[3];
  bool  isT[3];
  #pragma unroll
  for (int j = 0; j < 3; ++j) {
    const int rp = 12*G + 3*q + j;      // interleaved row
    const int u_ = rp >> 2;
    const int qg = rp & 3;              // 0=i 1=f 2=g 3=o
    const int grow = qg*96 + u_;        // original gate row
    const float* ph = W_hh + grow*96 + 24*c4;
    #pragma unroll
    for (int i = 0; i < 24; ++i) wh[j][i] = ph[i];
    #pragma unroll
    for (int i = 0; i < 6; ++i) {
      const int cc = 6*c4 + i;
      wx[j][i] = (cc < 21) ? W_ih[grow*21 + cc] : 0.f;
    }
    bg[j]  = (c4 == 0) ? (b_ih[grow] + b_hh[grow]) : 0.f;
    isT[j] = (qg == 2);
  }
  const int un = 3*G + lu;              // owned unit (valid when lu<3)

  if (tid < 256) ((float*)vv)[tid] = 0.f;
  for (int i = tid; i < 3*HH; i += 512) lastk[i] = 0.f;
  for (int i = tid; i < 192;  i += 512) et[i] = eemb[i];
  for (int i = tid; i < 24;   i += 512) rt[i] = remb[i];

  float c_state = 0.f;
  const int L = len[b];                 // state frozen past L; outputs past L unused

  for (int t0 = 0; t0 < L; t0 += CH) {
    // ---- stage 1: coalesced seq load + index load ----
    for (int i = tid; i < CH*FF; i += 512) {
      const int r = i / 12;
      const int c = i - r*12;
      xch[r][c] = seq[(size_t)b*(TT*FF) + (size_t)t0*FF + i];
    }
    if (tid < CH) {
      evb[tid] = ev [b*TT + t0 + tid];
      rsb[tid] = rsi[b*TT + t0 + tid];
    }
    __syncthreads();
    // ---- stage 2: embedding gather + zero pad (cols 12..31) ----
    for (int i = tid; i < CH*20; i += 512) {
      const int r  = i / 20;
      const int cc = i - r*20 + 12;
      float val;
      if (cc < 18)      val = et[evb[r]*6 + (cc-12)];
      else if (cc < 21) val = rt[rsb[r]*3 + (cc-18)];
      else              val = 0.f;
      xch[r][cc] = val;
    }
    __syncthreads();

    const int nr = min(CH, L - t0);
    for (int r = 0; r < nr; ++r) {
      const int p = (t0 + r) & 1;
      // ---- h slice (quad-broadcast, conflict-free) + x slice ----
      const float* hp = vv[p] + 24*c4;
      float hb[24];
      #pragma unroll
      for (int i = 0; i < 6; ++i) *(float4*)&hb[4*i] = ((const float4*)hp)[i];
      const float* xp = &xch[r][6*c4];
      float xb[6];
      #pragma unroll
      for (int i = 0; i < 3; ++i) *(float2*)&xb[2*i] = ((const float2*)xp)[i];

      // ---- 90 FMA + quad butterfly per row ----
      float S[3];
      #pragma unroll
      for (int j = 0; j < 3; ++j) {
        float a0 = bg[j], a1 = 0.f, a2 = 0.f;
        #pragma unroll
        for (int i = 0; i < 8; ++i) {
          a0 = fmaf(wh[j][3*i+0], hb[3*i+0], a0);
          a1 = fmaf(wh[j][3*i+1], hb[3*i+1], a1);
          a2 = fmaf(wh[j][3*i+2], hb[3*i+2], a2);
        }
        a0 = fmaf(wx[j][0], xb[0], a0);
        a1 = fmaf(wx[j][1], xb[1], a1);
        a2 = fmaf(wx[j][2], xb[2], a2);
        a0 = fmaf(wx[j][3], xb[3], a0);
        a1 = fmaf(wx[j][4], xb[4], a1);
        a2 = fmaf(wx[j][5], xb[5], a2);
        float s = (a0 + a1) + a2;
        s += DPPF(s, QP_XOR1);           // quad butterfly: all 4 lanes get
        s += DPPF(s, QP_XOR2);           // the full 30x4=120-col dot
        S[j] = s;
      }
      // ---- activations (redundant per quad, parallel) ----
      float A[3];
      #pragma unroll
      for (int j = 0; j < 3; ++j) {
        const float s = S[j];
        const float arg = isT[j] ? (-2.f*L2E)*fabsf(s) : (-L2E)*s;
        const float e  = fast_exp2(arg);
        const float r1 = fast_rcp(1.f + e);
        A[j] = isT[j] ? copysignf((1.f - e)*r1, s) : r1;
      }
      // ---- cross-quad gathers (all lanes active; VALU rate) ----
      const float m1 = DPPF(A[0], SHL4);   // q0<-row3 (o0)
      const float m2 = DPPF(A[1], SHL4);   // q0<-row4 (i1)
      const float m3 = DPPF(A[2], SHL4);   // q0<-row5 (f1)
      const float m4 = DPPF(m1,  SHL4);    // q0<-row6 (g1)
      const float m5 = DPPF(m2,  SHL4);    // q0<-row7 (o1)
      const float s8 = DPPF(A[2], SHL8);   // q0<-row8 (i2)
      const float w9 = DPPF(A[0], SHL12);  // q0<-row9 (f2)
      const float wa = DPPF(A[1], SHL12);  // q0<-row10 (g2)
      const float wb = DPPF(A[2], SHL12);  // q0<-row11 (o2)
      // ---- unit update: lanes lu=0,1,2 own units 3G+lu ----
      if (lu < 3) {
        const float il = (lu==0) ? A[0] : ((lu==1) ? m2 : s8);
        const float fl = (lu==0) ? A[1] : ((lu==1) ? m3 : w9);
        const float gl = (lu==0) ? A[2] : ((lu==1) ? m4 : wa);
        const float ol = (lu==0) ? m1   : ((lu==1) ? m5 : wb);
        c_state = fmaf(fl, c_state, il*gl);
        const float e2 = fast_exp2((-2.f*L2E)*fabsf(c_state));
        const float th = copysignf((1.f - e2)*fast_rcp(1.f + e2), c_state);
        const float hn = ol * th;
        vv[p^1][un] = hn;
        const int kk = (t0 + r) + 3 - L;    // last-K ring: t in [L-3, L)
        if (kk >= 0) lastk[kk*96 + un] = hn;
      }
      __syncthreads();
    }
  }

  // ---- epilogue: h_fin = vv[L&1]; h_lastk = relu(W_mlp@lastk+b); out = W_fc@[h_fin|h_lastk]+b ----
  const float* hfin = vv[L & 1];
  if (tid < 192) {
    const int hh = tid / 96;
    const int m  = tid - hh*96;
    const float* wp = W_mlp + m*288 + hh*144;
    const float* xq = lastk + hh*144;
    float s = 0.f;
    #pragma unroll 8
    for (int i = 0; i < 144; ++i) s = fmaf(wp[i], xq[i], s);
    accs[tid] = s;
  }
  __syncthreads();
  if (tid < 96) {
    const float hl = accs[tid] + accs[96+tid] + b_mlp[tid];
    h2[96 + tid] = fmaxf(hl, 0.f);
    h2[tid] = hfin[tid];
  }
  __syncthreads();
  if (tid < 128) {
    const int o  = tid >> 6;
    const int ll = tid & 63;
    const float* wf = W_fc + o*192 + 3*ll;
    float s = fmaf(wf[0], h2[3*ll+0], fmaf(wf[1], h2[3*ll+1], wf[2]*h2[3*ll+2]));
    #pragma unroll
    for (int off = 32; off > 0; off >>= 1) s += __shfl_down(s, off);
    if (ll == 0) out[b*2 + o] = s + b_fc[o];
  }
}

extern "C" void kernel_launch(void* const* d_in, const int* in_sizes, int n_in,
                              void* d_out, int out_size, void* d_ws, size_t ws_size,
                              hipStream_t stream) {
  const float* seq   = (const float*)d_in[0];
  const int*   ev    = (const int*)  d_in[1];
  const int*   rsi   = (const int*)  d_in[2];
  const int*   len   = (const int*)  d_in[3];
  const float* eemb  = (const float*)d_in[4];
  const float* remb  = (const float*)d_in[5];
  const float* W_ih  = (const float*)d_in[6];
  const float* W_hh  = (const float*)d_in[7];
  const float* b_ih  = (const float*)d_in[8];
  const float* b_hh  = (const float*)d_in[9];
  const float* W_mlp = (const float*)d_in[10];
  const float* b_mlp = (const float*)d_in[11];
  const float* W_fc  = (const float*)d_in[12];
  const float* b_fc  = (const float*)d_in[13];

  hipLaunchKernelGGL(lstm_persist, dim3(256), dim3(512), 0, stream,
                     seq, ev, rsi, len, eemb, remb, W_ih, W_hh, b_ih, b_hh,
                     W_mlp, b_mlp, W_fc, b_fc, (float*)d_out);
}